// Round 9
// baseline (18735.255 us; speedup 1.0000x reference)
//
#include <hip/hip_runtime.h>
#include <hip/hip_fp16.h>

typedef _Float16 h2 __attribute__((ext_vector_type(2)));
typedef _Float16 h4 __attribute__((ext_vector_type(4)));
typedef _Float16 h8 __attribute__((ext_vector_type(8)));

// ---- ws layout (float-word offsets) ----
// Wave-coalesced blocked layouts (as R8):
//  160-op rows: block = 8 rows x [t0: lane*16B][t1: 1KB+lane*16B][t2: 2KB+lane*8B] = 1280 halfs
//  320-op rows: block = 8 rows x 5 pieces of 1KB (lane*16B) = 2560 halfs
//  UQT: block = 4 rows x 4 pieces of 1KB = 2048 halfs (16 lanes/row)
#define OFF_EW     0u                        // 24 x 64 blk x 1280 halfs: clamp(exp(2*WUq)), pads 1.0
#define OFF_UQT    983040u                   // 24 x 38 blk x 2048 halfs (rows>=150 zero)
#define OFF_WAV    1916928u                  // 75 blk x 1280: r<150: 2*Wv | 150..599: w_hh
#define OFF_WG     1964928u                  // 38 blk x 2560: collapsed Wg rows 300..599
#define OFF_WIH    2013568u                  // 57 blk x 2560: w_ih (rows>=450 zero)
#define OFF_WQST   2086528u                  // f32 [150][150] collapsed Wq^T
#define OFF_WPST   2109028u                  // f32 [150][150] collapsed Wp^T
#define OFF_WUP2   2131528u                  // f32 [512][24][152]: 2*Wup (pads 0), streamed
#define WS_FLOATS  3999304u                  // 16.0 MB (same as passing R3)

__device__ __forceinline__ float fast_rcp(float x) { return __builtin_amdgcn_rcpf(x); }
__device__ __forceinline__ float fast_tanh(float x) {
  return 1.f - 2.f * fast_rcp(__expf(2.f * x) + 1.f);
}
__device__ __forceinline__ float fast_sigmoid(float x) {
  return fast_rcp(1.f + __expf(-x));
}

#if defined(__has_builtin)
#if __has_builtin(__builtin_amdgcn_fdot2)
#define HAVE_FDOT2 1
#endif
#endif
__device__ __forceinline__ float fdot2(h2 a, h2 b, float c) {
#ifdef HAVE_FDOT2
  return __builtin_amdgcn_fdot2(a, b, c, false);
#else
  return c + (float)a[0] * (float)b[0] + (float)a[1] * (float)b[1];
#endif
}
#define SV2(V, i) (__builtin_shufflevector((V), (V), (i), (i) + 1))
__device__ __forceinline__ float fdot8h(h8 w, const h2* v, float acc) {
  acc = fdot2(SV2(w, 0), v[0], acc);
  acc = fdot2(SV2(w, 2), v[1], acc);
  acc = fdot2(SV2(w, 4), v[2], acc);
  acc = fdot2(SV2(w, 6), v[3], acc);
  return acc;
}
__device__ __forceinline__ float fdot4h(h4 w, const h2* v, float acc) {
  acc = fdot2(SV2(w, 0), v[0], acc);
  acc = fdot2(SV2(w, 2), v[1], acc);
  return acc;
}

// forward store index (halfs) for 160-op blocked layout: row r, pos p
__device__ __forceinline__ int idx160(int r, int p) {
  int j = p / 20, off = p % 20, lw = (r & 7) * 8 + j, blk = r >> 3;
  if (off < 8)  return blk * 1280 + lw * 8 + off;
  if (off < 16) return blk * 1280 + 512 + lw * 8 + (off - 8);
  return blk * 1280 + 1024 + lw * 4 + (off - 16);
}

// ---------- prep ----------
__global__ void prep_weights(const float* __restrict__ Wq, const float* __restrict__ Wp,
                             const float* __restrict__ Wv, const float* __restrict__ Wg,
                             const float* __restrict__ w_ih, const float* __restrict__ w_hh,
                             float* __restrict__ ws) {
  float* wqsT = ws + OFF_WQST;
  float* wpsT = ws + OFF_WPST;
  _Float16* WAV = (_Float16*)(ws + OFF_WAV);
  _Float16* WGh = (_Float16*)(ws + OFF_WG);
  _Float16* WIHh = (_Float16*)(ws + OFF_WIH);

  int idx = blockIdx.x * blockDim.x + threadIdx.x;
  int n = gridDim.x * blockDim.x;

  for (int i = idx; i < 150 * 150; i += n) {
    int d = i / 150, h = i - d * 150;
    wqsT[i] = Wq[h * 300 + d] + Wq[h * 300 + d + 150];
    wpsT[i] = Wp[h * 300 + d] + Wp[h * 300 + d + 150];
  }
  for (int i = idx; i < 75 * 1280; i += n) {  // WAV
    int blk = i / 1280, w_ = i - blk * 1280;
    int lw, off;
    if (w_ < 512)       { lw = w_ >> 3;           off = w_ & 7; }
    else if (w_ < 1024) { lw = (w_ - 512) >> 3;   off = 8 + ((w_ - 512) & 7); }
    else                { lw = (w_ - 1024) >> 2;  off = 16 + ((w_ - 1024) & 3); }
    int gl = lw >> 3, j = lw & 7, r = blk * 8 + gl, p = j * 20 + off;
    float v = 0.f;
    if (p < 150) v = (r < 150) ? 2.f * Wv[r * 150 + p] : w_hh[(r - 150) * 150 + p];
    WAV[i] = (_Float16)v;
  }
  for (int i = idx; i < 38 * 2560; i += n) {  // WG
    int blk = i / 2560, w_ = i - blk * 2560;
    int t = w_ >> 9, lw = (w_ - (t << 9)) >> 3, off = t * 8 + (w_ & 7);
    int gl = lw >> 3, j = lw & 7, r = blk * 8 + gl, p = j * 40 + off;
    float v = 0.f;
    if (r < 300) {
      int row = (300 + r) * 600;
      if (p < 150) v = Wg[row + p] + Wg[row + 150 + p];
      else if (p >= 160 && p < 310) { int d = p - 160; v = Wg[row + 300 + d] + Wg[row + 450 + d]; }
    }
    WGh[i] = (_Float16)v;
  }
  for (int i = idx; i < 57 * 2560; i += n) {  // WIH
    int blk = i / 2560, w_ = i - blk * 2560;
    int t = w_ >> 9, lw = (w_ - (t << 9)) >> 3, off = t * 8 + (w_ & 7);
    int gl = lw >> 3, j = lw & 7, r = blk * 8 + gl, p = j * 40 + off;
    float v = (r < 450 && p < 300) ? w_ih[r * 300 + p] : 0.f;
    WIHh[i] = (_Float16)v;
  }
}

__global__ __launch_bounds__(192) void prep_ew(const float* __restrict__ uq, float* __restrict__ ws) {
  const float* wqsT = ws + OFF_WQST;
  _Float16* EW = (_Float16*)(ws + OFF_EW);
  const int l = blockIdx.x, b = blockIdx.y;
  __shared__ float sx[150], sDot[150];
  const int t = threadIdx.x;
  if (t < 150) sx[t] = uq[((size_t)l * 24 + b) * 150 + t];
  __syncthreads();
  if (t < 150) {
    float acc = 0.f;
    for (int d = 0; d < 150; ++d) acc += sx[d] * wqsT[d * 150 + t];
    sDot[t] = acc;
  }
  __syncthreads();
  if (t < 160) {
    float val = 1.f;
    if (t < 150) {
      val = __expf(2.f * sDot[t]);
      val = fminf(fmaxf(val, 1e-7f), 60000.f);
    }
    EW[(size_t)b * 81920 + idx160(l, t)] = (_Float16)val;
  }
}

// WUP2[l][b][t<152] fp32 = 2 * up_l,b . wpsT[:,t] (pads 0) — R3's passing numerics
__global__ __launch_bounds__(192) void prep_wup2(const float* __restrict__ up, float* __restrict__ ws) {
  const float* wpsT = ws + OFF_WPST;
  float* W2 = ws + OFF_WUP2;
  const int l = blockIdx.x, b = blockIdx.y;
  __shared__ float sx[150];
  const int t = threadIdx.x;
  if (t < 150) sx[t] = up[((size_t)l * 24 + b) * 150 + t];
  __syncthreads();
  if (t < 152) {
    float val = 0.f;
    if (t < 150) {
      float acc = 0.f;
      for (int d = 0; d < 150; ++d) acc += sx[d] * wpsT[d * 150 + t];
      val = 2.f * acc;
    }
    W2[((size_t)l * 24 + b) * 152 + t] = val;
  }
}

__global__ void prep_uqt(const float* __restrict__ uq, float* __restrict__ ws) {
  _Float16* UQT = (_Float16*)(ws + OFF_UQT);
  int idx = blockIdx.x * blockDim.x + threadIdx.x;
  int n = gridDim.x * blockDim.x;
  for (int m = idx; m < 24 * 38 * 2048; m += n) {
    int b = m / (38 * 2048);
    int i = m - b * 38 * 2048;
    int blk = i >> 11, w_ = i & 2047;
    int t = w_ >> 9, lw = (w_ - (t << 9)) >> 3, off = t * 8 + (w_ & 7);
    int gl = lw >> 4, j16 = lw & 15, r = blk * 4 + gl, l = j16 * 32 + off;
    UQT[m] = (_Float16)((r < 150) ? uq[((size_t)l * 24 + b) * 150 + r] : 0.f);
  }
}

// ---------- main: 256 blocks, 24 workers (3 per XCD) ----------
__global__ __launch_bounds__(1024, 4) void pq_main(
    const float* __restrict__ up, const float* __restrict__ v0,
    const float* __restrict__ Vfull, const float* __restrict__ b_ih,
    const float* __restrict__ b_hh, const float* __restrict__ ws,
    float* __restrict__ out) {
  const int blk0 = blockIdx.x;
  const int x = blk0 & 7, s = blk0 >> 3;
  const int t3 = (s == 0) ? 0 : (s == 10) ? 1 : (s == 20) ? 2 : -1;
  if (t3 < 0) return;
  const int b = x + 8 * t3;
  const int tid = threadIdx.x;

  const _Float16* EWh  = (const _Float16*)(ws + OFF_EW) + (size_t)b * 81920;
  const _Float16* UQTh = (const _Float16*)(ws + OFF_UQT) + (size_t)b * 77824;
  const _Float16* WAV  = (const _Float16*)(ws + OFF_WAV);
  const _Float16* WGh  = (const _Float16*)(ws + OFF_WG);
  const _Float16* WIHh = (const _Float16*)(ws + OFF_WIH);
  const float*    WUP2 = ws + OFF_WUP2;

  __shared__ float sTmpA[608];     // [0,150): 2*Wv@v | [150,600): w_hh@v (persists to GRU)
  __shared__ float sWup2[160];     // 2*Wup_i fp32 (prefetched; pads 0)
  __shared__ float eyl[160];       // ey, pads 1.0
  __shared__ float vvl[160];       // V, pads 0
  __shared__ float sS[512] __attribute__((aligned(16)));
  __shared__ float sC[152];
  __shared__ float sGip[456], sBih[456], sBhh[456];
  __shared__ float sVl[152];
  __shared__ float sSumV;
  __shared__ h2 sAhp2[320];  // softmax a: 16 chunks x 40 halfs (32 real + 8 pad), 16B-aligned h8 stores
  __shared__ h2 vop2[80];    // v operand fp16 (pads 0)
  __shared__ h2 ox2[160];    // [up | c] operand (up@0..149, c@160..309, rest 0)
  __shared__ h2 cq2[160];    // c_ operand (0..299, pads 0)
  _Float16* sAhx = (_Float16*)sAhp2;
  _Float16* vop = (_Float16*)vop2;
  _Float16* ox  = (_Float16*)ox2;
  _Float16* cq  = (_Float16*)cq2;

  const int wv = tid >> 6;
  const int lw = tid & 63;
  const int gl = (tid >> 3) & 7, j = tid & 7;
  const int j16 = tid & 15;
  const int gl4 = (tid >> 4) & 3;

  // ---- init ----
  if (tid < 160) {
    vop[tid] = (_Float16)((tid < 150) ? v0[b * 150 + tid] : 0.f);
    vvl[tid] = (tid < 150) ? Vfull[b * 150 + tid] : 0.f;
  } else if (tid < 480) {
    int p = tid - 160;
    ox[p] = (_Float16)0.f;
    cq[p] = (_Float16)0.f;
  } else if (tid < 490) {
    sWup2[150 + (tid - 480)] = 0.f;
  }
  if (tid >= 512 && tid < 968) {
    int p = tid - 512;
    sBih[p] = (p < 450) ? b_ih[p] : 0.f;
    sBhh[p] = (p < 450) ? b_hh[p] : 0.f;
  }
  if (tid < 152) sVl[tid] = (tid < 150) ? v0[b * 150 + tid] : 0.f;
  __syncthreads();
  if (tid < 150) ox[tid] = (_Float16)up[(size_t)b * 150 + tid];   // up[0][b]
  if (tid >= 192 && tid < 256) {
    int ln = tid - 192;
    float sm = 0.f;
    for (int h = ln; h < 150; h += 64) sm += vvl[h];
    #pragma unroll
    for (int off = 32; off; off >>= 1) sm += __shfl_xor(sm, off, 64);
    if (ln == 0) sSumV = sm;
  }
  __syncthreads();

  float upre = 0.f;

  for (int i = 0; i < 512; ++i) {
    // ======== A: tmpA = [2Wv; w_hh] @ v (loads hoisted); prefetch WUP2_i, up_{i+1} ========
    {
      float wup2pre = 0.f;
      if (tid >= 640 && tid < 792) {
        wup2pre = WUP2[((size_t)i * 24 + b) * 152 + (tid - 640)];
      } else if (tid >= 800 && tid < 950) {
        int inx = (i + 1 < 512) ? i + 1 : i;
        upre = up[((size_t)inx * 24 + b) * 150 + (tid - 800)];
      }
      h8 LA[5], LB[5]; h4 LC[5];
      #pragma unroll
      for (int it = 0; it < 5; ++it) {
        const int bk = wv + (it << 4);
        if (bk < 75) {
          const _Float16* base = WAV + bk * 1280;
          LA[it] = *(const h8*)(base + lw * 8);
          LB[it] = *(const h8*)(base + 512 + lw * 8);
          LC[it] = *(const h4*)(base + 1024 + lw * 4);
        }
      }
      h2 va[10];
      #pragma unroll
      for (int t = 0; t < 10; ++t) va[t] = vop2[j * 10 + t];
      #pragma unroll
      for (int it = 0; it < 5; ++it) {
        const int bk = wv + (it << 4);
        if (bk < 75) {
          float acc = 0.f;
          acc = fdot8h(LA[it], &va[0], acc);
          acc = fdot8h(LB[it], &va[4], acc);
          acc = fdot4h(LC[it], &va[8], acc);
          acc += __shfl_xor(acc, 1, 64);
          acc += __shfl_xor(acc, 2, 64);
          acc += __shfl_xor(acc, 4, 64);
          if (j == 0) sTmpA[bk * 8 + gl] = acc;
        }
      }
      if (tid >= 640 && tid < 792) sWup2[tid - 640] = wup2pre;
    }
    __syncthreads();
    // ======== A2: ey (tiny) ========
    if (tid < 160) {
      eyl[tid] = (tid < 150) ? fminf(__expf(sWup2[tid] + sTmpA[tid]), 1e30f) : 1.f;
    }
    __syncthreads();
    // ======== P1: s[l] = sumV - 2*sum_h V_h / (EW*ey + 1), loads hoisted ========
    {
      float ey[20], vv[20];
      #pragma unroll
      for (int t = 0; t < 20; ++t) { ey[t] = eyl[j * 20 + t]; vv[t] = vvl[j * 20 + t]; }
      h8 LA[4], LB[4]; h4 LC[4];
      #pragma unroll
      for (int it = 0; it < 4; ++it) {
        const _Float16* base = EWh + (wv + (it << 4)) * 1280;
        LA[it] = *(const h8*)(base + lw * 8);
        LB[it] = *(const h8*)(base + 512 + lw * 8);
        LC[it] = *(const h4*)(base + 1024 + lw * 4);
      }
      #pragma unroll
      for (int it = 0; it < 4; ++it) {
        h2 w[10];
        w[0] = SV2(LA[it], 0); w[1] = SV2(LA[it], 2); w[2] = SV2(LA[it], 4); w[3] = SV2(LA[it], 6);
        w[4] = SV2(LB[it], 0); w[5] = SV2(LB[it], 2); w[6] = SV2(LB[it], 4); w[7] = SV2(LB[it], 6);
        w[8] = SV2(LC[it], 0); w[9] = SV2(LC[it], 2);
        float acc = 0.f;
        #pragma unroll
        for (int t = 0; t < 10; ++t) {
          float x1 = fmaf((float)w[t][0], ey[2 * t],     1.f);
          float y1 = fmaf((float)w[t][1], ey[2 * t + 1], 1.f);
          float num = fmaf(vv[2 * t], y1, vv[2 * t + 1] * x1);
          acc = fmaf(num, fast_rcp(x1 * y1), acc);
        }
        acc += __shfl_xor(acc, 1, 64);
        acc += __shfl_xor(acc, 2, 64);
        acc += __shfl_xor(acc, 4, 64);
        if (j == 0) sS[(wv + (it << 4)) * 8 + gl] = sSumV - 2.f * acc;
      }
    }
    __syncthreads();
    // ======== SM: barrier-free softmax (all waves reduce redundantly; wave 0 writes) ========
    {
      const float4* s4 = (const float4*)sS;
      float4 Sa = s4[lw * 2], Sb = s4[lw * 2 + 1];
      float m = fmaxf(fmaxf(fmaxf(Sa.x, Sa.y), fmaxf(Sa.z, Sa.w)),
                      fmaxf(fmaxf(Sb.x, Sb.y), fmaxf(Sb.z, Sb.w)));
      #pragma unroll
      for (int off = 32; off; off >>= 1) m = fmaxf(m, __shfl_xor(m, off, 64));
      float e0 = __expf(Sa.x - m), e1 = __expf(Sa.y - m), e2 = __expf(Sa.z - m), e3 = __expf(Sa.w - m);
      float e4 = __expf(Sb.x - m), e5 = __expf(Sb.y - m), e6 = __expf(Sb.z - m), e7 = __expf(Sb.w - m);
      float z = ((e0 + e1) + (e2 + e3)) + ((e4 + e5) + (e6 + e7));
      #pragma unroll
      for (int off = 32; off; off >>= 1) z += __shfl_xor(z, off, 64);
      if (wv == 0) {
        float r = fast_rcp(z);
        h8 o;
        o[0] = (_Float16)(e0 * r); o[1] = (_Float16)(e1 * r);
        o[2] = (_Float16)(e2 * r); o[3] = (_Float16)(e3 * r);
        o[4] = (_Float16)(e4 * r); o[5] = (_Float16)(e5 * r);
        o[6] = (_Float16)(e6 * r); o[7] = (_Float16)(e7 * r);
        *(h8*)(sAhx + (lw >> 2) * 40 + (lw & 3) * 8) = o;   // chunk stride 40 halfs (16B-aligned)
      }
    }
    __syncthreads();
    // ======== P2: c = a @ Uq rows (16-lane groups, loads hoisted) ========
    {
      h2 aa[16];
      #pragma unroll
      for (int t = 0; t < 16; ++t) aa[t] = sAhp2[j16 * 20 + t];
      h8 LW[3][4];
      #pragma unroll
      for (int it = 0; it < 3; ++it) {
        const int bk = wv + (it << 4);
        if (bk < 38) {
          const _Float16* base = UQTh + bk * 2048;
          LW[it][0] = *(const h8*)(base + lw * 8);
          LW[it][1] = *(const h8*)(base + 512 + lw * 8);
          LW[it][2] = *(const h8*)(base + 1024 + lw * 8);
          LW[it][3] = *(const h8*)(base + 1536 + lw * 8);
        }
      }
      #pragma unroll
      for (int it = 0; it < 3; ++it) {
        const int bk = wv + (it << 4);
        if (bk < 38) {
          float acc = 0.f;
          acc = fdot8h(LW[it][0], &aa[0], acc);
          acc = fdot8h(LW[it][1], &aa[4], acc);
          acc = fdot8h(LW[it][2], &aa[8], acc);
          acc = fdot8h(LW[it][3], &aa[12], acc);
          acc += __shfl_xor(acc, 1, 64);
          acc += __shfl_xor(acc, 2, 64);
          acc += __shfl_xor(acc, 4, 64);
          acc += __shfl_xor(acc, 8, 64);
          const int r = bk * 4 + gl4;
          if (j16 == 0 && r < 150) {
            sC[r] = acc;
            ox[160 + r] = (_Float16)acc;
          }
        }
      }
    }
    __syncthreads();
    // ======== P3: g = sigmoid(WG @ [up|c]); c_ = g * c (loads hoisted) ========
    {
      h2 xa[20];
      #pragma unroll
      for (int t = 0; t < 20; ++t) xa[t] = ox2[j * 20 + t];
      h8 LW[3][5];
      #pragma unroll
      for (int it = 0; it < 3; ++it) {
        const int bk = wv + (it << 4);
        if (bk < 38) {
          const _Float16* base = WGh + bk * 2560;
          #pragma unroll
          for (int t = 0; t < 5; ++t) LW[it][t] = *(const h8*)(base + t * 512 + lw * 8);
        }
      }
      #pragma unroll
      for (int it = 0; it < 3; ++it) {
        const int bk = wv + (it << 4);
        if (bk < 38) {
          float acc = 0.f;
          #pragma unroll
          for (int t = 0; t < 5; ++t) acc = fdot8h(LW[it][t], &xa[4 * t], acc);
          acc += __shfl_xor(acc, 1, 64);
          acc += __shfl_xor(acc, 2, 64);
          acc += __shfl_xor(acc, 4, 64);
          const int r = bk * 8 + gl;
          if (j == 0 && r < 300) {
            float gg = fast_sigmoid(acc);
            int cj = (r >= 150) ? r - 150 : r;
            cq[r] = (_Float16)(gg * sC[cj]);
          }
        }
      }
    }
    __syncthreads();
    // ======== P4: gi = WIH @ c_ (loads hoisted) ========
    {
      h2 xa[20];
      #pragma unroll
      for (int t = 0; t < 20; ++t) xa[t] = cq2[j * 20 + t];
      h8 LW[4][5];
      #pragma unroll
      for (int it = 0; it < 4; ++it) {
        const int bk = wv + (it << 4);
        if (bk < 57) {
          const _Float16* base = WIHh + bk * 2560;
          #pragma unroll
          for (int t = 0; t < 5; ++t) LW[it][t] = *(const h8*)(base + t * 512 + lw * 8);
        }
      }
      #pragma unroll
      for (int it = 0; it < 4; ++it) {
        const int bk = wv + (it << 4);
        if (bk < 57) {
          float acc = 0.f;
          #pragma unroll
          for (int t = 0; t < 5; ++t) acc = fdot8h(LW[it][t], &xa[4 * t], acc);
          acc += __shfl_xor(acc, 1, 64);
          acc += __shfl_xor(acc, 2, 64);
          acc += __shfl_xor(acc, 4, 64);
          const int r = bk * 8 + gl;
          if (j == 0 && r < 450) sGip[r] = acc;
        }
      }
    }
    __syncthreads();
    // ======== GRU (gh = sTmpA[150+...] inlined) + commit prefetched up_{i+1} ========
    if (tid < 150) {
      const int h = tid;
      float gh_r = sTmpA[150 + h] + sBhh[h];
      float gh_z = sTmpA[300 + h] + sBhh[150 + h];
      float gh_n = sTmpA[450 + h] + sBhh[300 + h];
      float rg = fast_sigmoid(sGip[h]       + sBih[h]       + gh_r);
      float zg = fast_sigmoid(sGip[150 + h] + sBih[150 + h] + gh_z);
      float nn = fast_tanh(sGip[300 + h] + sBih[300 + h] + rg * gh_n);
      float vn = (1.f - zg) * nn + zg * sVl[h];
      sVl[h] = vn;
      vop[h] = (_Float16)vn;
      out[((size_t)i * 24 + b) * 150 + h] = vn;
    } else if (tid >= 800 && tid < 950 && i + 1 < 512) {
      ox[tid - 800] = (_Float16)upre;
    }
    __syncthreads();
  }
}

extern "C" void kernel_launch(void* const* d_in, const int* in_sizes, int n_in,
                              void* d_out, int out_size, void* d_ws, size_t ws_size,
                              hipStream_t stream) {
  const float* up   = (const float*)d_in[0];
  const float* uq   = (const float*)d_in[1];
  const float* v0   = (const float*)d_in[2];
  const float* V    = (const float*)d_in[3];
  const float* Wp   = (const float*)d_in[4];
  const float* Wq   = (const float*)d_in[5];
  const float* Wv   = (const float*)d_in[6];
  const float* Wg   = (const float*)d_in[7];
  const float* w_ih = (const float*)d_in[8];
  const float* w_hh = (const float*)d_in[9];
  const float* b_ih = (const float*)d_in[10];
  const float* b_hh = (const float*)d_in[11];
  float* ws  = (float*)d_ws;
  float* out = (float*)d_out;

  if (ws_size < (size_t)WS_FLOATS * sizeof(float)) return;

  prep_weights<<<256, 256, 0, stream>>>(Wq, Wp, Wv, Wg, w_ih, w_hh, ws);
  prep_uqt<<<512, 256, 0, stream>>>(uq, ws);
  prep_ew<<<dim3(512, 24), 192, 0, stream>>>(uq, ws);
  prep_wup2<<<dim3(512, 24), 192, 0, stream>>>(up, ws);
  pq_main<<<256, 1024, 0, stream>>>(up, v0, V, b_ih, b_hh, ws, out);
}

// Round 10
// 16298.946 us; speedup vs baseline: 1.1495x; 1.1495x over previous
//
#include <hip/hip_runtime.h>
#include <hip/hip_fp16.h>

typedef _Float16 h2 __attribute__((ext_vector_type(2)));
typedef _Float16 h4 __attribute__((ext_vector_type(4)));
typedef _Float16 h8 __attribute__((ext_vector_type(8)));

// ---- ws layout (float-word offsets) ----
// Wave-coalesced blocked layouts (as R8/R9):
//  160-op rows: block = 8 rows x [t0: lane*16B][t1: 1KB+lane*16B][t2: 2KB+lane*8B] = 1280 halfs
//  320-op rows: block = 8 rows x 5 pieces of 1KB (lane*16B) = 2560 halfs
//  UQT: block = 4 rows x 4 pieces of 1KB = 2048 halfs (16 lanes/row)
#define OFF_EW     0u                        // 24 x 64 blk x 1280 halfs: clamp(exp(2*WUq)), pads 1.0
#define OFF_UQT    983040u                   // 24 x 38 blk x 2048 halfs (rows>=150 zero)
#define OFF_WAV    1916928u                  // 75 blk x 1280: r<150: 2*Wv | 150..599: w_hh
#define OFF_WG     1964928u                  // 38 blk x 2560: collapsed Wg rows 300..599
#define OFF_WIH    2013568u                  // 57 blk x 2560: w_ih (rows>=450 zero)
#define OFF_WQST   2086528u                  // f32 [150][150] collapsed Wq^T
#define OFF_WPST   2109028u                  // f32 [150][150] collapsed Wp^T
#define OFF_WUP2   2131528u                  // f32 [512][24][152]: 2*Wup (pads 0), streamed
#define WS_FLOATS  3999304u                  // 16.0 MB

__device__ __forceinline__ float fast_rcp(float x) { return __builtin_amdgcn_rcpf(x); }
__device__ __forceinline__ float fast_tanh(float x) {
  return 1.f - 2.f * fast_rcp(__expf(2.f * x) + 1.f);
}
__device__ __forceinline__ float fast_sigmoid(float x) {
  return fast_rcp(1.f + __expf(-x));
}

#if defined(__has_builtin)
#if __has_builtin(__builtin_amdgcn_fdot2)
#define HAVE_FDOT2 1
#endif
#endif
__device__ __forceinline__ float fdot2(h2 a, h2 b, float c) {
#ifdef HAVE_FDOT2
  return __builtin_amdgcn_fdot2(a, b, c, false);
#else
  return c + (float)a[0] * (float)b[0] + (float)a[1] * (float)b[1];
#endif
}
#define SV2(V, i) (__builtin_shufflevector((V), (V), (i), (i) + 1))
__device__ __forceinline__ float fdot8h(h8 w, const h2* v, float acc) {
  acc = fdot2(SV2(w, 0), v[0], acc);
  acc = fdot2(SV2(w, 2), v[1], acc);
  acc = fdot2(SV2(w, 4), v[2], acc);
  acc = fdot2(SV2(w, 6), v[3], acc);
  return acc;
}
__device__ __forceinline__ float fdot4h(h4 w, const h2* v, float acc) {
  acc = fdot2(SV2(w, 0), v[0], acc);
  acc = fdot2(SV2(w, 2), v[1], acc);
  return acc;
}

// forward store index (halfs) for 160-op blocked layout: row r, pos p
__device__ __forceinline__ int idx160(int r, int p) {
  int j = p / 20, off = p % 20, lw = (r & 7) * 8 + j, blk = r >> 3;
  if (off < 8)  return blk * 1280 + lw * 8 + off;
  if (off < 16) return blk * 1280 + 512 + lw * 8 + (off - 8);
  return blk * 1280 + 1024 + lw * 4 + (off - 16);
}

// ---------- prep (unchanged from R9) ----------
__global__ void prep_weights(const float* __restrict__ Wq, const float* __restrict__ Wp,
                             const float* __restrict__ Wv, const float* __restrict__ Wg,
                             const float* __restrict__ w_ih, const float* __restrict__ w_hh,
                             float* __restrict__ ws) {
  float* wqsT = ws + OFF_WQST;
  float* wpsT = ws + OFF_WPST;
  _Float16* WAV = (_Float16*)(ws + OFF_WAV);
  _Float16* WGh = (_Float16*)(ws + OFF_WG);
  _Float16* WIHh = (_Float16*)(ws + OFF_WIH);

  int idx = blockIdx.x * blockDim.x + threadIdx.x;
  int n = gridDim.x * blockDim.x;

  for (int i = idx; i < 150 * 150; i += n) {
    int d = i / 150, h = i - d * 150;
    wqsT[i] = Wq[h * 300 + d] + Wq[h * 300 + d + 150];
    wpsT[i] = Wp[h * 300 + d] + Wp[h * 300 + d + 150];
  }
  for (int i = idx; i < 75 * 1280; i += n) {  // WAV
    int blk = i / 1280, w_ = i - blk * 1280;
    int lw, off;
    if (w_ < 512)       { lw = w_ >> 3;           off = w_ & 7; }
    else if (w_ < 1024) { lw = (w_ - 512) >> 3;   off = 8 + ((w_ - 512) & 7); }
    else                { lw = (w_ - 1024) >> 2;  off = 16 + ((w_ - 1024) & 3); }
    int gl = lw >> 3, j = lw & 7, r = blk * 8 + gl, p = j * 20 + off;
    float v = 0.f;
    if (p < 150) v = (r < 150) ? 2.f * Wv[r * 150 + p] : w_hh[(r - 150) * 150 + p];
    WAV[i] = (_Float16)v;
  }
  for (int i = idx; i < 38 * 2560; i += n) {  // WG
    int blk = i / 2560, w_ = i - blk * 2560;
    int t = w_ >> 9, lw = (w_ - (t << 9)) >> 3, off = t * 8 + (w_ & 7);
    int gl = lw >> 3, j = lw & 7, r = blk * 8 + gl, p = j * 40 + off;
    float v = 0.f;
    if (r < 300) {
      int row = (300 + r) * 600;
      if (p < 150) v = Wg[row + p] + Wg[row + 150 + p];
      else if (p >= 160 && p < 310) { int d = p - 160; v = Wg[row + 300 + d] + Wg[row + 450 + d]; }
    }
    WGh[i] = (_Float16)v;
  }
  for (int i = idx; i < 57 * 2560; i += n) {  // WIH
    int blk = i / 2560, w_ = i - blk * 2560;
    int t = w_ >> 9, lw = (w_ - (t << 9)) >> 3, off = t * 8 + (w_ & 7);
    int gl = lw >> 3, j = lw & 7, r = blk * 8 + gl, p = j * 40 + off;
    float v = (r < 450 && p < 300) ? w_ih[r * 300 + p] : 0.f;
    WIHh[i] = (_Float16)v;
  }
}

__global__ __launch_bounds__(192) void prep_ew(const float* __restrict__ uq, float* __restrict__ ws) {
  const float* wqsT = ws + OFF_WQST;
  _Float16* EW = (_Float16*)(ws + OFF_EW);
  const int l = blockIdx.x, b = blockIdx.y;
  __shared__ float sx[150], sDot[150];
  const int t = threadIdx.x;
  if (t < 150) sx[t] = uq[((size_t)l * 24 + b) * 150 + t];
  __syncthreads();
  if (t < 150) {
    float acc = 0.f;
    for (int d = 0; d < 150; ++d) acc += sx[d] * wqsT[d * 150 + t];
    sDot[t] = acc;
  }
  __syncthreads();
  if (t < 160) {
    float val = 1.f;
    if (t < 150) {
      val = __expf(2.f * sDot[t]);
      val = fminf(fmaxf(val, 1e-7f), 60000.f);
    }
    EW[(size_t)b * 81920 + idx160(l, t)] = (_Float16)val;
  }
}

__global__ __launch_bounds__(192) void prep_wup2(const float* __restrict__ up, float* __restrict__ ws) {
  const float* wpsT = ws + OFF_WPST;
  float* W2 = ws + OFF_WUP2;
  const int l = blockIdx.x, b = blockIdx.y;
  __shared__ float sx[150];
  const int t = threadIdx.x;
  if (t < 150) sx[t] = up[((size_t)l * 24 + b) * 150 + t];
  __syncthreads();
  if (t < 152) {
    float val = 0.f;
    if (t < 150) {
      float acc = 0.f;
      for (int d = 0; d < 150; ++d) acc += sx[d] * wpsT[d * 150 + t];
      val = 2.f * acc;
    }
    W2[((size_t)l * 24 + b) * 152 + t] = val;
  }
}

__global__ void prep_uqt(const float* __restrict__ uq, float* __restrict__ ws) {
  _Float16* UQT = (_Float16*)(ws + OFF_UQT);
  int idx = blockIdx.x * blockDim.x + threadIdx.x;
  int n = gridDim.x * blockDim.x;
  for (int m = idx; m < 24 * 38 * 2048; m += n) {
    int b = m / (38 * 2048);
    int i = m - b * 38 * 2048;
    int blk = i >> 11, w_ = i & 2047;
    int t = w_ >> 9, lw = (w_ - (t << 9)) >> 3, off = t * 8 + (w_ & 7);
    int gl = lw >> 4, j16 = lw & 15, r = blk * 4 + gl, l = j16 * 32 + off;
    UQT[m] = (_Float16)((r < 150) ? uq[((size_t)l * 24 + b) * 150 + r] : 0.f);
  }
}

// ---------- main: 256 blocks, 24 workers (3 per XCD) ----------
__global__ __attribute__((amdgpu_waves_per_eu(4, 4))) __launch_bounds__(1024)
void pq_main(
    const float* __restrict__ up, const float* __restrict__ v0,
    const float* __restrict__ Vfull, const float* __restrict__ b_ih,
    const float* __restrict__ b_hh, const float* __restrict__ ws,
    float* __restrict__ out) {
  const int blk0 = blockIdx.x;
  const int x = blk0 & 7, s = blk0 >> 3;
  const int t3 = (s == 0) ? 0 : (s == 10) ? 1 : (s == 20) ? 2 : -1;
  if (t3 < 0) return;
  const int b = x + 8 * t3;
  const int tid = threadIdx.x;

  const _Float16* EWh  = (const _Float16*)(ws + OFF_EW) + (size_t)b * 81920;
  const _Float16* UQTh = (const _Float16*)(ws + OFF_UQT) + (size_t)b * 77824;
  const _Float16* WAV  = (const _Float16*)(ws + OFF_WAV);
  const _Float16* WGh  = (const _Float16*)(ws + OFF_WG);
  const _Float16* WIHh = (const _Float16*)(ws + OFF_WIH);
  const float*    WUP2 = ws + OFF_WUP2;

  __shared__ float sTmpA[608];     // [0,150): 2*Wv@v | [150,600): w_hh@v (persists to GRU)
  __shared__ float sWup2[160];     // 2*Wup_i fp32 (prefetched; pads 0)
  __shared__ float vvl[160];       // V, pads 0
  __shared__ float sSp[528] __attribute__((aligned(16)));  // scores, stride 33 per 32-chunk
  __shared__ float sC[152];
  __shared__ float sGip[456], sBih[456], sBhh[456];
  __shared__ float sVl[152];
  __shared__ float sSumV;
  __shared__ h2 vop2[80];    // v operand fp16 (pads 0)
  __shared__ h2 ox2[160];    // [up | c] operand (up@0..149, c@160..309, rest 0)
  __shared__ h2 cq2[160];    // c_ operand (0..299, pads 0)
  _Float16* vop = (_Float16*)vop2;
  _Float16* ox  = (_Float16*)ox2;
  _Float16* cq  = (_Float16*)cq2;

  const int wv = tid >> 6;
  const int lw = tid & 63;
  const int gl = (tid >> 3) & 7, j = tid & 7;
  const int j16 = tid & 15;
  const int gl4 = (tid >> 4) & 3;

  // ---- init ----
  if (tid < 160) {
    vop[tid] = (_Float16)((tid < 150) ? v0[b * 150 + tid] : 0.f);
    vvl[tid] = (tid < 150) ? Vfull[b * 150 + tid] : 0.f;
  } else if (tid < 480) {
    int p = tid - 160;
    ox[p] = (_Float16)0.f;
    cq[p] = (_Float16)0.f;
  } else if (tid < 490) {
    sWup2[150 + (tid - 480)] = 0.f;
  }
  if (tid >= 512 && tid < 968) {
    int p = tid - 512;
    sBih[p] = (p < 450) ? b_ih[p] : 0.f;
    sBhh[p] = (p < 450) ? b_hh[p] : 0.f;
  }
  if (tid < 152) sVl[tid] = (tid < 150) ? v0[b * 150 + tid] : 0.f;
  __syncthreads();
  if (tid < 150) ox[tid] = (_Float16)up[(size_t)b * 150 + tid];   // up[0][b]
  if (tid >= 192 && tid < 256) {
    int ln = tid - 192;
    float sm = 0.f;
    for (int h = ln; h < 150; h += 64) sm += vvl[h];
    #pragma unroll
    for (int off = 32; off; off >>= 1) sm += __shfl_xor(sm, off, 64);
    if (ln == 0) sSumV = sm;
  }
  __syncthreads();

  float upre = 0.f;

  for (int i = 0; i < 512; ++i) {
    // ======== A: tmpA = [2Wv; w_hh] @ v, depth-2 pipelined; prefetch WUP2_i, up_{i+1} ========
    {
      float wup2pre = 0.f;
      if (tid >= 640 && tid < 792) {
        wup2pre = WUP2[((size_t)i * 24 + b) * 152 + (tid - 640)];
      } else if (tid >= 800 && tid < 950) {
        int inx = (i + 1 < 512) ? i + 1 : i;
        upre = up[((size_t)inx * 24 + b) * 150 + (tid - 800)];
      }
      h8 LA[2], LB[2]; h4 LC[2];
      {
        const _Float16* base = WAV + wv * 1280;
        LA[0] = *(const h8*)(base + lw * 8);
        LB[0] = *(const h8*)(base + 512 + lw * 8);
        LC[0] = *(const h4*)(base + 1024 + lw * 4);
        base += 16 * 1280;
        LA[1] = *(const h8*)(base + lw * 8);
        LB[1] = *(const h8*)(base + 512 + lw * 8);
        LC[1] = *(const h4*)(base + 1024 + lw * 4);
      }
      h2 va[10];
      #pragma unroll
      for (int t = 0; t < 10; ++t) va[t] = vop2[j * 10 + t];
      #pragma unroll
      for (int it = 0; it < 5; ++it) {
        const int bk = wv + (it << 4);
        const int sl = it & 1;
        if (bk < 75) {
          float acc = 0.f;
          acc = fdot8h(LA[sl], &va[0], acc);
          acc = fdot8h(LB[sl], &va[4], acc);
          acc = fdot4h(LC[sl], &va[8], acc);
          acc += __shfl_xor(acc, 1, 64);
          acc += __shfl_xor(acc, 2, 64);
          acc += __shfl_xor(acc, 4, 64);
          if (j == 0) sTmpA[bk * 8 + gl] = acc;
        }
        const int bkn = bk + 32;
        if (it + 2 < 5 && bkn < 75) {
          const _Float16* base = WAV + bkn * 1280;
          LA[sl] = *(const h8*)(base + lw * 8);
          LB[sl] = *(const h8*)(base + 512 + lw * 8);
          LC[sl] = *(const h4*)(base + 1024 + lw * 4);
        }
      }
      if (tid >= 640 && tid < 792) sWup2[tid - 640] = wup2pre;
    }
    __syncthreads();
    // ======== P1: ey inline (per-wave), s[l] = sumV - 2*sum_h V_h/(EW*ey+1), depth-2 ========
    {
      h8 LA[2], LB[2]; h4 LC[2];
      {
        const _Float16* base = EWh + wv * 1280;
        LA[0] = *(const h8*)(base + lw * 8);
        LB[0] = *(const h8*)(base + 512 + lw * 8);
        LC[0] = *(const h4*)(base + 1024 + lw * 4);
        base += 16 * 1280;
        LA[1] = *(const h8*)(base + lw * 8);
        LB[1] = *(const h8*)(base + 512 + lw * 8);
        LC[1] = *(const h4*)(base + 1024 + lw * 4);
      }
      float ey[20], vv[20];
      #pragma unroll
      for (int t = 0; t < 20; ++t) {
        const int p = j * 20 + t;
        ey[t] = fminf(__expf(sWup2[p] + sTmpA[p]), 1e30f);
        vv[t] = vvl[p];
      }
      #pragma unroll
      for (int it = 0; it < 4; ++it) {
        const int sl = it & 1;
        h2 w[10];
        w[0] = SV2(LA[sl], 0); w[1] = SV2(LA[sl], 2); w[2] = SV2(LA[sl], 4); w[3] = SV2(LA[sl], 6);
        w[4] = SV2(LB[sl], 0); w[5] = SV2(LB[sl], 2); w[6] = SV2(LB[sl], 4); w[7] = SV2(LB[sl], 6);
        w[8] = SV2(LC[sl], 0); w[9] = SV2(LC[sl], 2);
        float acc = 0.f;
        #pragma unroll
        for (int t = 0; t < 10; ++t) {
          float x1 = fmaf((float)w[t][0], ey[2 * t],     1.f);
          float y1 = fmaf((float)w[t][1], ey[2 * t + 1], 1.f);
          float num = fmaf(vv[2 * t], y1, vv[2 * t + 1] * x1);
          acc = fmaf(num, fast_rcp(x1 * y1), acc);
        }
        const int bkn = wv + ((it + 2) << 4);
        if (it + 2 < 4) {
          const _Float16* base = EWh + bkn * 1280;
          LA[sl] = *(const h8*)(base + lw * 8);
          LB[sl] = *(const h8*)(base + 512 + lw * 8);
          LC[sl] = *(const h4*)(base + 1024 + lw * 4);
        }
        acc += __shfl_xor(acc, 1, 64);
        acc += __shfl_xor(acc, 2, 64);
        acc += __shfl_xor(acc, 4, 64);
        if (j == 0) {
          const int l = (wv + (it << 4)) * 8 + gl;
          sSp[l + (l >> 5)] = sSumV - 2.f * acc;
        }
      }
    }
    __syncthreads();
    // ======== P2: softmax inline (per-wave, chunk j16) + c = a @ Uq, depth-2 ========
    {
      h8 LW[2][4];
      {
        const _Float16* base = UQTh + wv * 2048;
        LW[0][0] = *(const h8*)(base + lw * 8);
        LW[0][1] = *(const h8*)(base + 512 + lw * 8);
        LW[0][2] = *(const h8*)(base + 1024 + lw * 8);
        LW[0][3] = *(const h8*)(base + 1536 + lw * 8);
        base += 16 * 2048;
        LW[1][0] = *(const h8*)(base + lw * 8);
        LW[1][1] = *(const h8*)(base + 512 + lw * 8);
        LW[1][2] = *(const h8*)(base + 1024 + lw * 8);
        LW[1][3] = *(const h8*)(base + 1536 + lw * 8);
      }
      // softmax for my chunk (lanes with same j16 compute identically)
      float sv[32];
      float m = -3.4e38f;
      {
        const float* cbase = sSp + j16 * 33;
        #pragma unroll
        for (int t = 0; t < 32; ++t) { sv[t] = cbase[t]; m = fmaxf(m, sv[t]); }
      }
      #pragma unroll
      for (int off = 32; off; off >>= 1) m = fmaxf(m, __shfl_xor(m, off, 64));
      float z = 0.f;
      #pragma unroll
      for (int t = 0; t < 32; ++t) { sv[t] = __expf(sv[t] - m); z += sv[t]; }
      #pragma unroll
      for (int off = 32; off; off >>= 1) z += __shfl_xor(z, off, 64);
      z *= 0.25f;   // each chunk counted by 4 lanes
      const float rz = fast_rcp(z);
      h2 aa[16];
      #pragma unroll
      for (int t = 0; t < 16; ++t) {
        h2 o; o[0] = (_Float16)(sv[2 * t] * rz); o[1] = (_Float16)(sv[2 * t + 1] * rz);
        aa[t] = o;
      }
      #pragma unroll
      for (int it = 0; it < 3; ++it) {
        const int bk = wv + (it << 4);
        const int sl = it & 1;
        if (bk < 38) {
          float acc = 0.f;
          acc = fdot8h(LW[sl][0], &aa[0], acc);
          acc = fdot8h(LW[sl][1], &aa[4], acc);
          acc = fdot8h(LW[sl][2], &aa[8], acc);
          acc = fdot8h(LW[sl][3], &aa[12], acc);
          acc += __shfl_xor(acc, 1, 64);
          acc += __shfl_xor(acc, 2, 64);
          acc += __shfl_xor(acc, 4, 64);
          acc += __shfl_xor(acc, 8, 64);
          const int r = bk * 4 + gl4;
          if (j16 == 0 && r < 150) {
            sC[r] = acc;
            ox[160 + r] = (_Float16)acc;
          }
        }
        const int bkn = bk + 32;
        if (it + 2 < 3 && bkn < 38) {
          const _Float16* base = UQTh + bkn * 2048;
          LW[sl][0] = *(const h8*)(base + lw * 8);
          LW[sl][1] = *(const h8*)(base + 512 + lw * 8);
          LW[sl][2] = *(const h8*)(base + 1024 + lw * 8);
          LW[sl][3] = *(const h8*)(base + 1536 + lw * 8);
        }
      }
    }
    __syncthreads();
    // ======== P3: g = sigmoid(WG @ [up|c]); c_ = g * c, depth-2 ========
    {
      h8 LW[2][5];
      {
        const _Float16* base = WGh + wv * 2560;
        #pragma unroll
        for (int t = 0; t < 5; ++t) LW[0][t] = *(const h8*)(base + t * 512 + lw * 8);
        if (wv + 16 < 38) {
          base += 16 * 2560;
          #pragma unroll
          for (int t = 0; t < 5; ++t) LW[1][t] = *(const h8*)(base + t * 512 + lw * 8);
        }
      }
      h2 xa[20];
      #pragma unroll
      for (int t = 0; t < 20; ++t) xa[t] = ox2[j * 20 + t];
      #pragma unroll
      for (int it = 0; it < 3; ++it) {
        const int bk = wv + (it << 4);
        const int sl = it & 1;
        if (bk < 38) {
          float acc = 0.f;
          #pragma unroll
          for (int t = 0; t < 5; ++t) acc = fdot8h(LW[sl][t], &xa[4 * t], acc);
          acc += __shfl_xor(acc, 1, 64);
          acc += __shfl_xor(acc, 2, 64);
          acc += __shfl_xor(acc, 4, 64);
          const int r = bk * 8 + gl;
          if (j == 0 && r < 300) {
            float gg = fast_sigmoid(acc);
            int cj = (r >= 150) ? r - 150 : r;
            cq[r] = (_Float16)(gg * sC[cj]);
          }
        }
        const int bkn = bk + 32;
        if (it + 2 < 3 && bkn < 38) {
          const _Float16* base = WGh + bkn * 2560;
          #pragma unroll
          for (int t = 0; t < 5; ++t) LW[sl][t] = *(const h8*)(base + t * 512 + lw * 8);
        }
      }
    }
    __syncthreads();
    // ======== P4: gi = WIH @ c_, depth-2 ========
    {
      h8 LW[2][5];
      {
        const _Float16* base = WIHh + wv * 2560;
        #pragma unroll
        for (int t = 0; t < 5; ++t) LW[0][t] = *(const h8*)(base + t * 512 + lw * 8);
        base += 16 * 2560;
        #pragma unroll
        for (int t = 0; t < 5; ++t) LW[1][t] = *(const h8*)(base + t * 512 + lw * 8);
      }
      h2 xa[20];
      #pragma unroll
      for (int t = 0; t < 20; ++t) xa[t] = cq2[j * 20 + t];
      #pragma unroll
      for (int it = 0; it < 4; ++it) {
        const int bk = wv + (it << 4);
        const int sl = it & 1;
        if (bk < 57) {
          float acc = 0.f;
          #pragma unroll
          for (int t = 0; t < 5; ++t) acc = fdot8h(LW[sl][t], &xa[4 * t], acc);
          acc += __shfl_xor(acc, 1, 64);
          acc += __shfl_xor(acc, 2, 64);
          acc += __shfl_xor(acc, 4, 64);
          const int r = bk * 8 + gl;
          if (j == 0 && r < 450) sGip[r] = acc;
        }
        const int bkn = bk + 32;
        if (it + 2 < 4 && bkn < 57) {
          const _Float16* base = WIHh + bkn * 2560;
          #pragma unroll
          for (int t = 0; t < 5; ++t) LW[sl][t] = *(const h8*)(base + t * 512 + lw * 8);
        }
      }
    }
    __syncthreads();
    // ======== GRU (gh inlined from sTmpA) + commit prefetched up_{i+1} ========
    if (tid < 150) {
      const int h = tid;
      float gh_r = sTmpA[150 + h] + sBhh[h];
      float gh_z = sTmpA[300 + h] + sBhh[150 + h];
      float gh_n = sTmpA[450 + h] + sBhh[300 + h];
      float rg = fast_sigmoid(sGip[h]       + sBih[h]       + gh_r);
      float zg = fast_sigmoid(sGip[150 + h] + sBih[150 + h] + gh_z);
      float nn = fast_tanh(sGip[300 + h] + sBih[300 + h] + rg * gh_n);
      float vn = (1.f - zg) * nn + zg * sVl[h];
      sVl[h] = vn;
      vop[h] = (_Float16)vn;
      out[((size_t)i * 24 + b) * 150 + h] = vn;
    } else if (tid >= 800 && tid < 950 && i + 1 < 512) {
      ox[tid - 800] = (_Float16)upre;
    }
    __syncthreads();
  }
}

extern "C" void kernel_launch(void* const* d_in, const int* in_sizes, int n_in,
                              void* d_out, int out_size, void* d_ws, size_t ws_size,
                              hipStream_t stream) {
  const float* up   = (const float*)d_in[0];
  const float* uq   = (const float*)d_in[1];
  const float* v0   = (const float*)d_in[2];
  const float* V    = (const float*)d_in[3];
  const float* Wp   = (const float*)d_in[4];
  const float* Wq   = (const float*)d_in[5];
  const float* Wv   = (const float*)d_in[6];
  const float* Wg   = (const float*)d_in[7];
  const float* w_ih = (const float*)d_in[8];
  const float* w_hh = (const float*)d_in[9];
  const float* b_ih = (const float*)d_in[10];
  const float* b_hh = (const float*)d_in[11];
  float* ws  = (float*)d_ws;
  float* out = (float*)d_out;

  if (ws_size < (size_t)WS_FLOATS * sizeof(float)) return;

  prep_weights<<<256, 256, 0, stream>>>(Wq, Wp, Wv, Wg, w_ih, w_hh, ws);
  prep_uqt<<<512, 256, 0, stream>>>(uq, ws);
  prep_ew<<<dim3(512, 24), 192, 0, stream>>>(uq, ws);
  prep_wup2<<<dim3(512, 24), 192, 0, stream>>>(up, ws);
  pq_main<<<256, 1024, 0, stream>>>(up, v0, V, b_ih, b_hh, ws, out);
}